// Round 6
// baseline (196.553 us; speedup 1.0000x reference)
//
#include <hip/hip_runtime.h>
#include <hip/hip_bf16.h>
#include <math.h>

#define DIM   768
#define BATCH 32
#define SEQ   2048
#define SCALE 0.036084391824351615f  // 1/sqrt(768)

__device__ __forceinline__ float wave_sum(float v) {
#pragma unroll
    for (int o = 32; o > 0; o >>= 1) v += __shfl_xor(v, o, 64);
    return v;
}

__device__ __forceinline__ void fma4(float4& a, float s, const float4& c) {
    a.x += s * c.x; a.y += s * c.y; a.z += s * c.z; a.w += s * c.w;
}

// spin until *c >= target (thread 0 only), then acquire-fence + block barrier
__device__ __forceinline__ void spin_wait(int* c, int target) {
    if (threadIdx.x == 0) {
        while (atomicAdd(c, 0) < target) __builtin_amdgcn_s_sleep(2);
        __threadfence();
    }
    __syncthreads();
}
// block barrier + release-fence + signal
__device__ __forceinline__ void signal_done(int* c) {
    __syncthreads();
    if (threadIdx.x == 0) { __threadfence(); atomicAdd(c, 1); }
}

// ---------------------------------------------------------------------------
// Device GEMM tile (dual-source A, split-K chunk kc of 64):
// part[kc][Mtot][768] tile at (r0, jt).
// ---------------------------------------------------------------------------
__device__ __forceinline__ void gemm_tile(
        const float* __restrict__ A0, int lda0,
        const float* __restrict__ A1, int lda1, int ksplit,
        const float* __restrict__ Wp,
        float* __restrict__ part, int Mtot, int r0, int jt, int kc) {
    __shared__ float As[32][33];
    __shared__ float Ws[32][64];
    const int t = threadIdx.x;
    const int j = t & 63;
    const int bg = t >> 6;
    float acc[8];
#pragma unroll
    for (int i = 0; i < 8; i++) acc[i] = 0.f;

    for (int k0 = kc * 64; k0 < kc * 64 + 64; k0 += 32) {
        {
            int r  = t >> 3;
            int kk = (t & 7) * 4;
            int ka = k0 + kk;
            float4 av;
            if (ka < ksplit)
                av = *(const float4*)(A0 + (long)(r0 + r) * lda0 + ka);
            else
                av = *(const float4*)(A1 + (long)(r0 + r) * lda1 + (ka - ksplit));
            As[r][kk] = av.x; As[r][kk + 1] = av.y; As[r][kk + 2] = av.z; As[r][kk + 3] = av.w;
        }
#pragma unroll
        for (int i = 0; i < 2; i++) {
            int idx = t + i * 256;
            int row = idx >> 4, col4 = idx & 15;
            float4 wv = *(const float4*)(Wp + (long)(k0 + row) * DIM + jt + col4 * 4);
            *(float4*)&Ws[row][col4 * 4] = wv;
        }
        __syncthreads();
#pragma unroll 8
        for (int kk = 0; kk < 32; kk++) {
            float wv = Ws[kk][j];
#pragma unroll
            for (int i = 0; i < 8; i++) acc[i] += As[bg * 8 + i][kk] * wv;
        }
        __syncthreads();
    }
#pragma unroll
    for (int i = 0; i < 8; i++)
        part[((long)(kc * Mtot + r0 + bg * 8 + i)) * DIM + jt + j] = acc[i];
}

// ---------------------------------------------------------------------------
// Device LN row: reduce KC split-K partials + bias, LayerNorm+ReLU (+wattn).
// ---------------------------------------------------------------------------
__device__ __forceinline__ void ln_row(
        const float* __restrict__ part, int KC, int Mtot,
        const float* __restrict__ bp,
        const float* __restrict__ g, const float* __restrict__ b,
        const float* __restrict__ wattn,
        float* __restrict__ out, int row) {
    const int t = threadIdx.x;
    __shared__ float r1[4], r2[4];
    float x[3];
    float s = 0.f, ss = 0.f;
#pragma unroll
    for (int i = 0; i < 3; i++) {
        int jj = t + i * 256;
        float v = bp[jj];
        for (int kc = 0; kc < KC; kc++)
            v += part[((long)(kc * Mtot + row)) * DIM + jj];
        x[i] = v; s += v; ss += v * v;
    }
    float wsv = wave_sum(s), wss = wave_sum(ss);
    int lane = t & 63, wid = t >> 6;
    if (lane == 0) { r1[wid] = wsv; r2[wid] = wss; }
    __syncthreads();
    s  = r1[0] + r1[1] + r1[2] + r1[3];
    ss = r2[0] + r2[1] + r2[2] + r2[3];
    float mu = s * (1.f / DIM);
    float var = ss * (1.f / DIM) - mu * mu;
    float rs = rsqrtf(var + 1e-5f);
#pragma unroll
    for (int i = 0; i < 3; i++) {
        int jj = t + i * 256;
        float y = (x[i] - mu) * rs * g[jj] + b[jj];
        y = y > 0.f ? y : 0.f;
        if (wattn) y *= wattn[jj];
        out[(long)row * DIM + jj] = y;
    }
    __syncthreads();
}

// ---------------------------------------------------------------------------
// Pre-chain (one dispatch): gemm1 -> LN1 -> gemm2 -> LN2, spin-synced.
// grid = 432 x 256; __launch_bounds__(256,4) guarantees co-residency.
// ---------------------------------------------------------------------------
__global__ __launch_bounds__(256, 4) void pre_kernel(
        const float* __restrict__ question, const float* __restrict__ control,
        const float* __restrict__ W_pos, const float* __restrict__ b_pos,
        const int* __restrict__ step_ptr,
        const float* __restrict__ ln1_g, const float* __restrict__ ln1_b,
        const float* __restrict__ W_cq, const float* __restrict__ b_cq,
        const float* __restrict__ ln2_g, const float* __restrict__ ln2_b,
        const float* __restrict__ W_attn,
        float* __restrict__ part1, float* __restrict__ pa,
        float* __restrict__ part2, float* __restrict__ u,
        int* __restrict__ cnt) {
    const int i = blockIdx.x;
    const int st = step_ptr[0];
    int* c1 = cnt + 0; int* c2 = cnt + 1; int* c3 = cnt + 2;

    if (i < 144) {  // gemm1: question(32x768) @ W_pos[st], 12 kc x 12 jt
        gemm_tile(question, DIM, question, DIM, 1 << 30,
                  W_pos + (long)st * DIM * DIM, part1, 32, 0, (i % 12) * 64, i / 12);
        signal_done(c1);
    }
    if (i < 32) {   // LN1 -> pa
        spin_wait(c1, 144);
        ln_row(part1, 12, 32, b_pos + (long)st * DIM, ln1_g, ln1_b, nullptr, pa, i);
        signal_done(c2);
    }
    // gemm2: [control|pa](32x2304) @ W_cq, 36 kc x 12 jt (all 432 blocks)
    spin_wait(c2, 32);
    gemm_tile(control, 2 * DIM, pa, DIM, 2 * DIM, W_cq, part2, 32, 0,
              (i % 12) * 64, i / 12);
    signal_done(c3);
    if (i < 32) {   // LN2 * W_attn -> u
        spin_wait(c3, 432);
        ln_row(part2, 36, 32, b_cq, ln2_g, ln2_b, W_attn, u, i);
    }
}

// ---------------------------------------------------------------------------
// Fused attention (R3-proven core) + last-block-per-b combine epilogue.
// grid = (SEQ/64, BATCH), block = 256. No spins: epilogue is deadlock-free.
// ---------------------------------------------------------------------------
__global__ __launch_bounds__(256) void attn_main(
        const float* __restrict__ ctx, const float* __restrict__ u,
        const float* __restrict__ b_attn,
        const float* __restrict__ qm1, const float* __restrict__ qm2,
        float* __restrict__ w, float* __restrict__ zpart,
        float* __restrict__ pvec, int* __restrict__ cnt_b,
        float* __restrict__ A6, float* __restrict__ attn_out) {
    const int c = blockIdx.x;
    const int b = blockIdx.y;
    const int t = threadIdx.x;
    const int wave = t >> 6, lane = t & 63;
    __shared__ float4 us4[192];
    __shared__ float4 red[4][3][192];
    if (t < 192) us4[t] = ((const float4*)(u + (long)b * DIM))[t];
    __syncthreads();
    const float batt = b_attn[0];
    const long row0 = (long)b * SEQ + c * 64;

    float4 acc[3][3];
#pragma unroll
    for (int k = 0; k < 3; k++)
#pragma unroll
        for (int i = 0; i < 3; i++) acc[k][i] = make_float4(0.f, 0.f, 0.f, 0.f);
    float zacc[3] = {0.f, 0.f, 0.f};

#pragma unroll 1
    for (int g = 0; g < 4; g++) {
        const int rw = g * 16 + wave * 4;
        float4 cr[4][3];
        float d[4];
#pragma unroll
        for (int rr = 0; rr < 4; rr++) {
            const float4* crow = (const float4*)(ctx + (row0 + rw + rr) * DIM);
            float dd = 0.f;
#pragma unroll
            for (int i = 0; i < 3; i++) {
                float4 cv = crow[lane + i * 64];
                cr[rr][i] = cv;
                float4 uu = us4[lane + i * 64];
                dd += cv.x * uu.x + cv.y * uu.y + cv.z * uu.z + cv.w * uu.w;
            }
            d[rr] = wave_sum(dd);
        }
        float lw0 = (d[0] + batt) * SCALE;
        float lw1 = (d[1] + batt) * SCALE;
        float lw2 = (d[2] + batt) * SCALE;
        float lw3 = (d[3] + batt) * SCALE;
        if (lane < 4) {
            float v = lane == 0 ? lw0 : lane == 1 ? lw1 : lane == 2 ? lw2 : lw3;
            w[row0 + rw + lane] = v;
        }
        float mv = 0.f;
        if (lane < 4) mv = qm1[row0 + rw + lane];
        else if (lane < 8) mv = qm2[row0 + rw + lane - 4];
#pragma unroll
        for (int rr = 0; rr < 4; rr++) {
            float a1 = __shfl(mv, rr, 64);
            float a2 = __shfl(mv, rr + 4, 64);
            float lwr = rr == 0 ? lw0 : rr == 1 ? lw1 : rr == 2 ? lw2 : lw3;
            float ev = __expf(lwr);
            float e0 = (a1 != 0.f || a2 != 0.f) ? ev : 0.f;
            float e1 = (a1 != 0.f) ? ev : 0.f;
            float e2 = (a2 != 0.f) ? ev : 0.f;
            zacc[0] += e0; zacc[1] += e1; zacc[2] += e2;
#pragma unroll
            for (int i = 0; i < 3; i++) {
                fma4(acc[0][i], e0, cr[rr][i]);
                fma4(acc[1][i], e1, cr[rr][i]);
                fma4(acc[2][i], e2, cr[rr][i]);
            }
        }
    }
    if (lane == 0) {
        float* zp = zpart + ((long)(b * 32 + c) * 4 + wave) * 3;
        zp[0] = zacc[0]; zp[1] = zacc[1]; zp[2] = zacc[2];
    }
#pragma unroll
    for (int k = 0; k < 3; k++)
#pragma unroll
        for (int i = 0; i < 3; i++)
            red[wave][k][lane + i * 64] = acc[k][i];
    __syncthreads();
    for (int idx = t; idx < 576; idx += 256) {
        int k = idx / 192, col = idx - k * 192;
        float4 a = red[0][k][col], b2 = red[1][k][col];
        float4 c2 = red[2][k][col], d2 = red[3][k][col];
        float4 s;
        s.x = a.x + b2.x + c2.x + d2.x;
        s.y = a.y + b2.y + c2.y + d2.y;
        s.z = a.z + b2.z + c2.z + d2.z;
        s.w = a.w + b2.w + c2.w + d2.w;
        ((float4*)pvec)[((long)(b * 32 + c) * 3 + k) * 192 + col] = s;
    }

    // ---- last-block-per-b epilogue: combine + l2norm -> A6; attentions ----
    __shared__ int lastflag;
    __syncthreads();   // drain this block's pvec/zpart stores
    if (t == 0) {
        __threadfence();
        int old = atomicAdd(&cnt_b[b], 1);
        lastflag = (old == 31);
        if (old == 31) __threadfence();
    }
    __syncthreads();
    if (!lastflag) return;

    __shared__ float zr[4], sr[4];
#pragma unroll 1
    for (int k = 0; k < 3; k++) {
        float z = 0.f;
        if (t < 128) z = zpart[((long)(b * 32 + (t >> 2)) * 4 + (t & 3)) * 3 + k];
        z = wave_sum(z);
        if (lane == 0) zr[wave] = z;
        float v0 = 0.f, v1 = 0.f, v2 = 0.f;
        for (int cch = 0; cch < 32; cch++) {
            const float* p = pvec + ((long)(b * 32 + cch) * 3 + k) * DIM;
            v0 += p[t]; v1 += p[t + 256]; v2 += p[t + 512];
        }
        float ss = v0 * v0 + v1 * v1 + v2 * v2;
        float wss = wave_sum(ss);
        if (lane == 0) sr[wave] = wss;
        __syncthreads();
        float zz = zr[0] + zr[1] + zr[2] + zr[3];
        float sst = sr[0] + sr[1] + sr[2] + sr[3];
        float inv = 1.f / fmaxf(sqrtf(sst), 1e-12f);
        float vv[3] = {v0, v1, v2};
#pragma unroll
        for (int ii = 0; ii < 3; ii++) {
            int jj = t + ii * 256;
            float nv = vv[ii] * inv;
            if (k == 0) {
                A6[(long)b * (2 * DIM) + DIM + jj] = nv;
                A6[(long)(32 + b) * (2 * DIM) + DIM + jj] = nv;
            } else if (k == 1) {
                A6[(long)b * (2 * DIM) + jj] = nv;
            } else {
                A6[(long)(32 + b) * (2 * DIM) + jj] = nv;
            }
        }
        float iz = 1.f / zz;
#pragma unroll
        for (int ii = 0; ii < 8; ii++) {
            int s = t + ii * 256;
            float wv = w[(long)b * SEQ + s];
            float m1 = qm1[(long)b * SEQ + s];
            float m2 = qm2[(long)b * SEQ + s];
            bool act = (k == 0) ? (m1 != 0.f || m2 != 0.f)
                     : (k == 1) ? (m1 != 0.f) : (m2 != 0.f);
            attn_out[((long)b * 3 + k) * SEQ + s] = act ? __expf(wv) * iz : 0.f;
        }
        __syncthreads();
    }
}

// ---------------------------------------------------------------------------
// Post-chain (one dispatch): gemm3 -> dual-LN final, spin-synced.
// grid = 576 x 256.
// ---------------------------------------------------------------------------
__global__ __launch_bounds__(256, 4) void post_kernel(
        const float* __restrict__ A6, const float* __restrict__ W_fuse,
        float* __restrict__ part3, const float* __restrict__ b_fuse,
        const float* __restrict__ ln3_g, const float* __restrict__ ln3_b,
        const float* __restrict__ ln4_g, const float* __restrict__ ln4_b,
        float* __restrict__ nc, int* __restrict__ cnt) {
    const int i = blockIdx.x;
    const int t = threadIdx.x;
    int* c4 = cnt + 3;
    // gemm3: A6(64x1536) @ W_fuse, 24 kc x 2 r0 x 12 jt
    gemm_tile(A6, 2 * DIM, A6, 2 * DIM, 1 << 30, W_fuse, part3, 64,
              ((i / 12) % 2) * 32, (i % 12) * 64, i / 24);
    signal_done(c4);
    if (i < 64) {
        spin_wait(c4, 576);
        const int row = i;
        __shared__ float r1[4], r2[4];
        float x[3];
        float s = 0.f, ss = 0.f;
#pragma unroll
        for (int ii = 0; ii < 3; ii++) {
            int jj = t + ii * 256;
            float v = b_fuse[jj];
            for (int kc = 0; kc < 24; kc++)
                v += part3[((long)(kc * 64 + row)) * DIM + jj];
            x[ii] = v; s += v; ss += v * v;
        }
        float wsv = wave_sum(s), wss = wave_sum(ss);
        int lane = t & 63, wid = t >> 6;
        if (lane == 0) { r1[wid] = wsv; r2[wid] = wss; }
        __syncthreads();
        s  = r1[0] + r1[1] + r1[2] + r1[3];
        ss = r2[0] + r2[1] + r2[2] + r2[3];
        float mu = s * (1.f / DIM);
        float var = ss * (1.f / DIM) - mu * mu;
        float rs = rsqrtf(var + 1e-5f);
        const float* g  = (row < 32) ? ln3_g : ln4_g;
        const float* bb = (row < 32) ? ln3_b : ln4_b;
        int bidx = row & 31;
        int off  = (row < 32) ? 0 : DIM;
#pragma unroll
        for (int ii = 0; ii < 3; ii++) {
            int jj = t + ii * 256;
            float y = (x[ii] - mu) * rs * g[jj] + bb[jj];
            nc[(long)bidx * (2 * DIM) + off + jj] = y > 0.f ? y : 0.f;
        }
    }
}

extern "C" void kernel_launch(void* const* d_in, const int* in_sizes, int n_in,
                              void* d_out, int out_size, void* d_ws, size_t ws_size,
                              hipStream_t stream) {
    const int*   step     = (const int*)  d_in[0];
    const float* ctx      = (const float*)d_in[1];
    const float* question = (const float*)d_in[2];
    const float* control  = (const float*)d_in[3];
    const float* qm1      = (const float*)d_in[4];
    const float* qm2      = (const float*)d_in[5];
    const float* W_pos    = (const float*)d_in[8];
    const float* b_pos    = (const float*)d_in[9];
    const float* ln1_g    = (const float*)d_in[10];
    const float* ln1_b    = (const float*)d_in[11];
    const float* W_cq     = (const float*)d_in[12];
    const float* b_cq     = (const float*)d_in[13];
    const float* ln2_g    = (const float*)d_in[14];
    const float* ln2_b    = (const float*)d_in[15];
    const float* W_attn   = (const float*)d_in[16];
    const float* b_attn   = (const float*)d_in[17];
    const float* W_fuse   = (const float*)d_in[18];
    const float* b_fuse   = (const float*)d_in[19];
    const float* ln3_g    = (const float*)d_in[20];
    const float* ln3_b    = (const float*)d_in[21];
    const float* ln4_g    = (const float*)d_in[22];
    const float* ln4_b    = (const float*)d_in[23];

    int*   cnt  = (int*)d_ws;          // 64 ints (256 B)
    float* base = (float*)d_ws + 64;
    float* pa    = base;               // 24576
    float* u     = base + 24576;       // 24576
    float* w     = base + 49152;       // 65536
    float* zpart = base + 114688;      // 12288
    float* A6    = base + 126976;      // 98304
    float* part1 = base + 225280;      // 294912
    float* part2 = base + 520192;      // 884736
    float* part3 = base + 1404928;     // 1179648
    float* pvec  = base + 2584576;     // 2359296

    float* nc_out   = (float*)d_out;
    float* attn_out = (float*)d_out + BATCH * 2 * DIM;

    // zero the sync counters (graph-capturable, becomes a memset node)
    hipMemsetAsync(d_ws, 0, 256, stream);

    pre_kernel<<<432, 256, 0, stream>>>(
        question, control, W_pos, b_pos, step, ln1_g, ln1_b,
        W_cq, b_cq, ln2_g, ln2_b, W_attn, part1, pa, part2, u, cnt);

    attn_main<<<dim3(SEQ / 64, BATCH), 256, 0, stream>>>(
        ctx, u, b_attn, qm1, qm2, w, zpart, pvec, cnt + 8, A6, attn_out);

    post_kernel<<<576, 256, 0, stream>>>(
        A6, W_fuse, part3, b_fuse, ln3_g, ln3_b, ln4_g, ln4_b, nc_out, cnt);
}

// Round 7
// 102.837 us; speedup vs baseline: 1.9113x; 1.9113x over previous
//
#include <hip/hip_runtime.h>
#include <hip/hip_bf16.h>
#include <math.h>

#define DIM   768
#define BATCH 32
#define SEQ   2048
#define SCALE 0.036084391824351615f  // 1/sqrt(768)

__device__ __forceinline__ float wave_sum(float v) {
#pragma unroll
    for (int o = 32; o > 0; o >>= 1) v += __shfl_xor(v, o, 64);
    return v;
}

__device__ __forceinline__ void fma4(float4& a, float s, const float4& c) {
    a.x += s * c.x; a.y += s * c.y; a.z += s * c.z; a.w += s * c.w;
}

// ---------------------------------------------------------------------------
// Split-K partial GEMM with dual-source A (concat along K at ksplit):
// part[kc][Mtot][768] = A[M x 64-chunk] @ W[chunk x 768]
// grid = (768/64, Mtot/32, K/64), block = 256.
// ---------------------------------------------------------------------------
__global__ __launch_bounds__(256) void gemm_partial(
        const float* __restrict__ A0, int lda0,
        const float* __restrict__ A1, int lda1, int ksplit,
        const float* __restrict__ W,
        float* __restrict__ part, int Mtot,
        const int* __restrict__ step_ptr, int wstride) {
    const float* Wp = W + (step_ptr ? (long)step_ptr[0] * wstride : 0);
    const int jt = blockIdx.x * 64;
    const int r0 = blockIdx.y * 32;
    const int kc = blockIdx.z;
    __shared__ float As[32][33];
    __shared__ float Ws[32][64];
    const int t = threadIdx.x;
    const int j = t & 63;
    const int bg = t >> 6;
    float acc[8];
#pragma unroll
    for (int i = 0; i < 8; i++) acc[i] = 0.f;

    for (int k0 = kc * 64; k0 < kc * 64 + 64; k0 += 32) {
        {   // A tile 32x32
            int r  = t >> 3;
            int kk = (t & 7) * 4;
            int ka = k0 + kk;
            float4 av;
            if (ka < ksplit)
                av = *(const float4*)(A0 + (long)(r0 + r) * lda0 + ka);
            else
                av = *(const float4*)(A1 + (long)(r0 + r) * lda1 + (ka - ksplit));
            As[r][kk] = av.x; As[r][kk + 1] = av.y; As[r][kk + 2] = av.z; As[r][kk + 3] = av.w;
        }
#pragma unroll
        for (int i = 0; i < 2; i++) {  // W tile 32x64, float4 loads
            int idx = t + i * 256;
            int row = idx >> 4, col4 = idx & 15;
            float4 wv = *(const float4*)(Wp + (long)(k0 + row) * DIM + jt + col4 * 4);
            *(float4*)&Ws[row][col4 * 4] = wv;
        }
        __syncthreads();
#pragma unroll 8
        for (int kk = 0; kk < 32; kk++) {
            float wv = Ws[kk][j];
#pragma unroll
            for (int i = 0; i < 8; i++) acc[i] += As[bg * 8 + i][kk] * wv;
        }
        __syncthreads();
    }
#pragma unroll
    for (int i = 0; i < 8; i++)
        part[((long)(kc * Mtot + r0 + bg * 8 + i)) * DIM + jt + j] = acc[i];
}

// ---------------------------------------------------------------------------
// Reduce split-K partials + bias, LayerNorm+ReLU (+optional *wattn fold).
// grid = Mtot, block = 256.
// ---------------------------------------------------------------------------
__global__ __launch_bounds__(256) void reduce_ln(
        const float* __restrict__ part, int KC, int Mtot,
        const float* __restrict__ bias,
        const int* __restrict__ step_ptr, int bstride,
        const float* __restrict__ g, const float* __restrict__ b,
        const float* __restrict__ wattn,
        float* __restrict__ out) {
    const int row = blockIdx.x;
    const int t = threadIdx.x;
    const float* bp = bias + (step_ptr ? (long)step_ptr[0] * bstride : 0);
    __shared__ float r1[4], r2[4];
    float x[3];
    float s = 0.f, ss = 0.f;
#pragma unroll
    for (int i = 0; i < 3; i++) {
        int jj = t + i * 256;
        float v = bp[jj];
#pragma unroll 4
        for (int kc = 0; kc < KC; kc++)
            v += part[((long)(kc * Mtot + row)) * DIM + jj];
        x[i] = v; s += v; ss += v * v;
    }
    float wsv = wave_sum(s), wss = wave_sum(ss);
    int lane = t & 63, wid = t >> 6;
    if (lane == 0) { r1[wid] = wsv; r2[wid] = wss; }
    __syncthreads();
    s  = r1[0] + r1[1] + r1[2] + r1[3];
    ss = r2[0] + r2[1] + r2[2] + r2[3];
    float mu = s * (1.f / DIM);
    float var = ss * (1.f / DIM) - mu * mu;
    float rs = rsqrtf(var + 1e-5f);
#pragma unroll
    for (int i = 0; i < 3; i++) {
        int jj = t + i * 256;
        float y = (x[i] - mu) * rs * g[jj] + b[jj];
        y = y > 0.f ? y : 0.f;
        if (wattn) y *= wattn[jj];
        out[(long)row * DIM + jj] = y;
    }
}

// Final: reduce + bias, dual LN, ReLU -> next_control. grid = 64, block 256.
__global__ __launch_bounds__(256) void reduce_ln_final(
        const float* __restrict__ part, int KC,
        const float* __restrict__ bias,
        const float* __restrict__ g3, const float* __restrict__ b3,
        const float* __restrict__ g4, const float* __restrict__ b4,
        float* __restrict__ nc) {
    const int row = blockIdx.x;  // 0..63
    const int t = threadIdx.x;
    __shared__ float r1[4], r2[4];
    float x[3];
    float s = 0.f, ss = 0.f;
#pragma unroll
    for (int i = 0; i < 3; i++) {
        int jj = t + i * 256;
        float v = bias[jj];
#pragma unroll 4
        for (int kc = 0; kc < KC; kc++)
            v += part[((long)(kc * 64 + row)) * DIM + jj];
        x[i] = v; s += v; ss += v * v;
    }
    float wsv = wave_sum(s), wss = wave_sum(ss);
    int lane = t & 63, wid = t >> 6;
    if (lane == 0) { r1[wid] = wsv; r2[wid] = wss; }
    __syncthreads();
    s  = r1[0] + r1[1] + r1[2] + r1[3];
    ss = r2[0] + r2[1] + r2[2] + r2[3];
    float mu = s * (1.f / DIM);
    float var = ss * (1.f / DIM) - mu * mu;
    float rs = rsqrtf(var + 1e-5f);
    const float* g  = (row < 32) ? g3 : g4;
    const float* bb = (row < 32) ? b3 : b4;
    int bidx = row & 31;
    int off  = (row < 32) ? 0 : DIM;
#pragma unroll
    for (int i = 0; i < 3; i++) {
        int jj = t + i * 256;
        float y = (x[i] - mu) * rs * g[jj] + bb[jj];
        nc[(long)bidx * (2 * DIM) + off + jj] = y > 0.f ? y : 0.f;
    }
}

// ---------------------------------------------------------------------------
// Fused attention, single ctx read, LOW-LDS version for occupancy.
// grid = (SEQ/64, BATCH), block = 256 (4 waves x 4 rows x 4 groups = 64 rows).
// u in registers; cross-wave reduce via one 9.2 KB LDS buffer with
// sequential per-wave adds. Outputs: w logits; zpart[(b*32+c)*4+wave][3];
// pvec[(b*32+c)*3+k][768].
// ---------------------------------------------------------------------------
__global__ __launch_bounds__(256, 4) void attn_main(
        const float* __restrict__ ctx, const float* __restrict__ u,
        const float* __restrict__ b_attn,
        const float* __restrict__ qm1, const float* __restrict__ qm2,
        float* __restrict__ w, float* __restrict__ zpart,
        float* __restrict__ pvec) {
    const int c = blockIdx.x;
    const int b = blockIdx.y;
    const int t = threadIdx.x;
    const int wave = t >> 6, lane = t & 63;
    __shared__ float4 red[3][192];   // 9216 B
    const float batt = b_attn[0];
    const long row0 = (long)b * SEQ + c * 64;

    float4 uu[3];
#pragma unroll
    for (int i = 0; i < 3; i++)
        uu[i] = ((const float4*)(u + (long)b * DIM))[lane + i * 64];

    float4 acc[3][3];
#pragma unroll
    for (int k = 0; k < 3; k++)
#pragma unroll
        for (int i = 0; i < 3; i++) acc[k][i] = make_float4(0.f, 0.f, 0.f, 0.f);
    float zacc[3] = {0.f, 0.f, 0.f};

#pragma unroll 1
    for (int g = 0; g < 4; g++) {
        const int rw = g * 16 + wave * 4;
        float4 cr[4][3];
        float d[4];
#pragma unroll
        for (int rr = 0; rr < 4; rr++) {
            const float4* crow = (const float4*)(ctx + (row0 + rw + rr) * DIM);
            float dd = 0.f;
#pragma unroll
            for (int i = 0; i < 3; i++) {
                float4 cv = crow[lane + i * 64];
                cr[rr][i] = cv;
                dd += cv.x * uu[i].x + cv.y * uu[i].y + cv.z * uu[i].z + cv.w * uu[i].w;
            }
            d[rr] = wave_sum(dd);
        }
        float lw0 = (d[0] + batt) * SCALE;
        float lw1 = (d[1] + batt) * SCALE;
        float lw2 = (d[2] + batt) * SCALE;
        float lw3 = (d[3] + batt) * SCALE;
        if (lane < 4) {
            float v = lane == 0 ? lw0 : lane == 1 ? lw1 : lane == 2 ? lw2 : lw3;
            w[row0 + rw + lane] = v;
        }
        // masks for the 4 rows: lanes 0-3 qm1, lanes 4-7 qm2
        float mv = 0.f;
        if (lane < 4) mv = qm1[row0 + rw + lane];
        else if (lane < 8) mv = qm2[row0 + rw + lane - 4];
#pragma unroll
        for (int rr = 0; rr < 4; rr++) {
            float a1 = __shfl(mv, rr, 64);
            float a2 = __shfl(mv, rr + 4, 64);
            float lwr = rr == 0 ? lw0 : rr == 1 ? lw1 : rr == 2 ? lw2 : lw3;
            float ev = __expf(lwr);
            float e0 = (a1 != 0.f || a2 != 0.f) ? ev : 0.f;
            float e1 = (a1 != 0.f) ? ev : 0.f;
            float e2 = (a2 != 0.f) ? ev : 0.f;
            zacc[0] += e0; zacc[1] += e1; zacc[2] += e2;
#pragma unroll
            for (int i = 0; i < 3; i++) {
                fma4(acc[0][i], e0, cr[rr][i]);
                fma4(acc[1][i], e1, cr[rr][i]);
                fma4(acc[2][i], e2, cr[rr][i]);
            }
        }
    }
    if (lane == 0) {
        float* zp = zpart + ((long)(b * 32 + c) * 4 + wave) * 3;
        zp[0] = zacc[0]; zp[1] = zacc[1]; zp[2] = zacc[2];
    }
    // cross-wave reduce: wave 0 seeds, waves 1-3 add sequentially
    if (wave == 0) {
#pragma unroll
        for (int k = 0; k < 3; k++)
#pragma unroll
            for (int i = 0; i < 3; i++) red[k][lane + i * 64] = acc[k][i];
    }
    __syncthreads();
#pragma unroll 1
    for (int wv = 1; wv < 4; wv++) {
        if (wave == wv) {
#pragma unroll
            for (int k = 0; k < 3; k++)
#pragma unroll
                for (int i = 0; i < 3; i++) {
                    float4 r = red[k][lane + i * 64];
                    r.x += acc[k][i].x; r.y += acc[k][i].y;
                    r.z += acc[k][i].z; r.w += acc[k][i].w;
                    red[k][lane + i * 64] = r;
                }
        }
        __syncthreads();
    }
    for (int idx = t; idx < 576; idx += 256) {
        int k = idx / 192, col = idx - k * 192;
        ((float4*)pvec)[((long)(b * 32 + c) * 3 + k) * 192 + col] = red[k][col];
    }
}

// ---------------------------------------------------------------------------
// Combine chunk partials, l2-normalize -> A6; write attentions output.
// grid = (BATCH, 3): k=0 ncf, k=1 mc1, k=2 mc2. block = 256.
// ---------------------------------------------------------------------------
__global__ __launch_bounds__(256) void combine_norm(
        const float* __restrict__ zpart, const float* __restrict__ pvec,
        const float* __restrict__ w,
        const float* __restrict__ qm1, const float* __restrict__ qm2,
        float* __restrict__ A6, float* __restrict__ attn_out) {
    const int b = blockIdx.x, k = blockIdx.y;
    const int t = threadIdx.x;
    const int lane = t & 63, wid = t >> 6;
    __shared__ float r1[4], r2[4];
    // softmax denominator
    float z = 0.f;
    for (int j = t; j < 128; j += 256)
        z += zpart[((long)(b * 32 + (j >> 2)) * 4 + (j & 3)) * 3 + k];
    z = wave_sum(z);
    if (lane == 0) r1[wid] = z;
    __syncthreads();
    z = r1[0] + r1[1] + r1[2] + r1[3];
    // vector combine
    float v[3] = {0.f, 0.f, 0.f};
    for (int cch = 0; cch < 32; cch++) {
        const float* p = pvec + ((long)(b * 32 + cch) * 3 + k) * DIM;
#pragma unroll
        for (int i = 0; i < 3; i++) v[i] += p[t + i * 256];
    }
    float ss = v[0] * v[0] + v[1] * v[1] + v[2] * v[2];
    float wss = wave_sum(ss);
    if (lane == 0) r2[wid] = wss;
    __syncthreads();
    ss = r2[0] + r2[1] + r2[2] + r2[3];
    float inv = 1.f / fmaxf(sqrtf(ss), 1e-12f);
#pragma unroll
    for (int i = 0; i < 3; i++) {
        int jj = t + i * 256;
        float nv = v[i] * inv;
        if (k == 0) {
            A6[(long)b * (2 * DIM) + DIM + jj] = nv;
            A6[(long)(32 + b) * (2 * DIM) + DIM + jj] = nv;
        } else if (k == 1) {
            A6[(long)b * (2 * DIM) + jj] = nv;
        } else {
            A6[(long)(32 + b) * (2 * DIM) + jj] = nv;
        }
    }
    // attentions output for this (b, k)
    float iz = 1.f / z;
#pragma unroll
    for (int ii = 0; ii < 8; ii++) {
        int s = t + ii * 256;
        float wv = w[(long)b * SEQ + s];
        float m1 = qm1[(long)b * SEQ + s];
        float m2 = qm2[(long)b * SEQ + s];
        bool act = (k == 0) ? (m1 != 0.f || m2 != 0.f) : (k == 1) ? (m1 != 0.f) : (m2 != 0.f);
        attn_out[((long)b * 3 + k) * SEQ + s] = act ? __expf(wv) * iz : 0.f;
    }
}

extern "C" void kernel_launch(void* const* d_in, const int* in_sizes, int n_in,
                              void* d_out, int out_size, void* d_ws, size_t ws_size,
                              hipStream_t stream) {
    const int*   step     = (const int*)  d_in[0];
    const float* ctx      = (const float*)d_in[1];
    const float* question = (const float*)d_in[2];
    const float* control  = (const float*)d_in[3];
    const float* qm1      = (const float*)d_in[4];
    const float* qm2      = (const float*)d_in[5];
    const float* W_pos    = (const float*)d_in[8];
    const float* b_pos    = (const float*)d_in[9];
    const float* ln1_g    = (const float*)d_in[10];
    const float* ln1_b    = (const float*)d_in[11];
    const float* W_cq     = (const float*)d_in[12];
    const float* b_cq     = (const float*)d_in[13];
    const float* ln2_g    = (const float*)d_in[14];
    const float* ln2_b    = (const float*)d_in[15];
    const float* W_attn   = (const float*)d_in[16];
    const float* b_attn   = (const float*)d_in[17];
    const float* W_fuse   = (const float*)d_in[18];
    const float* b_fuse   = (const float*)d_in[19];
    const float* ln3_g    = (const float*)d_in[20];
    const float* ln3_b    = (const float*)d_in[21];
    const float* ln4_g    = (const float*)d_in[22];
    const float* ln4_b    = (const float*)d_in[23];

    float* ws    = (float*)d_ws;
    float* pa    = ws;             // 32*768   = 24576
    float* u     = ws + 24576;     // 32*768   = 24576
    float* w     = ws + 49152;     // 32*2048  = 65536
    float* zpart = ws + 114688;    // 1024*4*3 = 12288
    float* A6    = ws + 126976;    // 64*1536  = 98304
    float* big   = ws + 225280;    // shared: gemm partials (<=1179648) / pvec (2359296)

    float* nc_out   = (float*)d_out;
    float* attn_out = (float*)d_out + BATCH * 2 * DIM;

    // pa = ln_relu(question @ W_pos[step] + b_pos[step])
    gemm_partial<<<dim3(DIM / 64, 1, DIM / 64), 256, 0, stream>>>(
        question, DIM, question, DIM, 1 << 30, W_pos, big, 32, step, DIM * DIM);
    reduce_ln<<<BATCH, 256, 0, stream>>>(big, DIM / 64, 32, b_pos, step, DIM,
                                         ln1_g, ln1_b, nullptr, pa);

    // u = relu(ln([control | pa] @ W_cq + b_cq)) * W_attn   (dual-source A)
    gemm_partial<<<dim3(DIM / 64, 1, (3 * DIM) / 64), 256, 0, stream>>>(
        control, 2 * DIM, pa, DIM, 2 * DIM, W_cq, big, 32, nullptr, 0);
    reduce_ln<<<BATCH, 256, 0, stream>>>(big, (3 * DIM) / 64, 32, b_cq, nullptr, 0,
                                         ln2_g, ln2_b, W_attn, u);

    // fused single-read attention (low-LDS, high-occupancy)
    attn_main<<<dim3(SEQ / 64, BATCH), 256, 0, stream>>>(
        ctx, u, b_attn, qm1, qm2, w, zpart, big);

    // combine + l2norm -> A6; attentions output
    combine_norm<<<dim3(BATCH, 3), 256, 0, stream>>>(
        zpart, big, w, qm1, qm2, A6, attn_out);

    // fused GEMM + dual-LN -> next_control
    gemm_partial<<<dim3(DIM / 64, 2, (2 * DIM) / 64), 256, 0, stream>>>(
        A6, 2 * DIM, A6, 2 * DIM, 1 << 30, W_fuse, big, 64, nullptr, 0);
    reduce_ln_final<<<2 * BATCH, 256, 0, stream>>>(big, (2 * DIM) / 64, b_fuse,
                                                   ln3_g, ln3_b, ln4_g, ln4_b, nc_out);
}